// Round 4
// baseline (1094.645 us; speedup 1.0000x reference)
//
#include <hip/hip_runtime.h>
#include <stdint.h>
#include <stddef.h>

// WanSelfAttention on gfx950.
// Pipeline: convert x/w -> bf16, QKV GEMM (MFMA), rmsnorm+rope (bf16-faithful),
// V transpose, flash attention (MFMA, online softmax), out GEMM (MFMA, f32 out).
// Output dtype: float32 (reference returns f32; the harness label's "bf16" refers
// to bf16-floored thresholding, not the output buffer dtype).

#define LQ 2048
#define NHEADS 24
#define HDIM 128

typedef __attribute__((ext_vector_type(8))) short short8;
typedef __attribute__((ext_vector_type(4))) float f32x4;
typedef __attribute__((ext_vector_type(4))) unsigned short ushort4v;
typedef __attribute__((address_space(1))) uint32_t gu32;
typedef __attribute__((address_space(3))) uint32_t lu32;

__device__ __forceinline__ float btof(unsigned short u){
  union { float f; uint32_t i; } x; x.i = ((uint32_t)u) << 16; return x.f;
}
__device__ __forceinline__ unsigned short ftob(float f){
  uint32_t u = __builtin_bit_cast(uint32_t, f);
  u += 0x7fffu + ((u >> 16) & 1u);   // RTNE (finite inputs only)
  return (unsigned short)(u >> 16);
}
__device__ __forceinline__ float rb(float f){ return btof(ftob(f)); }

__device__ __forceinline__ void async_cp16(const void* g, void* l){
  __builtin_amdgcn_global_load_lds((gu32*)g, (lu32*)l, 16, 0, 0);
}

// ---------------- converters ----------------

__global__ __launch_bounds__(256) void k_convert_x(const float* __restrict__ x,
                                                   unsigned short* __restrict__ xb){
  int i = (blockIdx.x * 256 + threadIdx.x) * 4;
  float4 v = *(const float4*)(x + i);
  ushort4v o = { ftob(v.x), ftob(v.y), ftob(v.z), ftob(v.w) };
  *(ushort4v*)(xb + i) = o;
}

__global__ __launch_bounds__(256) void k_bias(const float* __restrict__ bq,
                                              const float* __restrict__ bk,
                                              const float* __restrict__ bv,
                                              float* __restrict__ bias9){
  int i = blockIdx.x * 256 + threadIdx.x;     // 0..9215
  const float* s = (i < 3072) ? bq : ((i < 6144) ? bk : bv);
  bias9[i] = s[i % 3072];
}

// Transpose f32 weights (K x N, row-major) into bf16 W^T (N x K) rows.
// grid: x = k-tile (48), y = n-tile (192: rows 0..9215 -> WTqkv, 9216.. -> woT)
__global__ __launch_bounds__(256) void k_wt(const float* __restrict__ wq,
                                            const float* __restrict__ wk,
                                            const float* __restrict__ wv,
                                            const float* __restrict__ wo,
                                            unsigned short* __restrict__ WTqkv,
                                            unsigned short* __restrict__ woT){
  __shared__ float tile[64][65];
  int k0 = blockIdx.x * 64;
  int n0g = blockIdx.y * 64;
  const float* src; unsigned short* dst; int col0, drow0;
  if (n0g < 9216){
    int sel = n0g / 3072;
    src = (sel == 0) ? wq : ((sel == 1) ? wk : wv);
    col0 = n0g % 3072; dst = WTqkv; drow0 = n0g;
  } else { src = wo; col0 = n0g - 9216; dst = woT; drow0 = n0g - 9216; }
  for (int i = 0; i < 16; i++){
    int idx = i * 256 + threadIdx.x;
    int r = idx >> 6, c = idx & 63;
    tile[r][c] = src[(size_t)(k0 + r) * 3072 + col0 + c];
  }
  __syncthreads();
  for (int i = 0; i < 16; i++){
    int idx = i * 256 + threadIdx.x;
    int rr = idx >> 6, cc = idx & 63;
    dst[(size_t)(drow0 + rr) * 3072 + k0 + cc] = ftob(tile[cc][rr]);
  }
}

// ---------------- GEMM: C[m][n] = sum_k A[m][k]*BT[n][k] + bias[n] ----------------
// m97 structure: 128x128 tile, BK=32, 4 waves (2x2), 4x4 MFMA tiles per wave.
template <bool OUT_BF16>
__global__ __launch_bounds__(256) void k_gemm(const unsigned short* __restrict__ A,
                                              const unsigned short* __restrict__ BT,
                                              const float* __restrict__ bias,
                                              void* __restrict__ Cout, int N, int K){
  __shared__ __align__(16) unsigned short As[128 * 32];
  __shared__ __align__(16) unsigned short Bs[128 * 32];
  int tid = threadIdx.x;
  int w = tid >> 6, lane = tid & 63;
  int quad = lane >> 4, l16 = lane & 15;
  int m0 = blockIdx.y * 128, n0 = blockIdx.x * 128;
  int wr = w >> 1, wc = w & 1;

  f32x4 acc[4][4] = {};

  int srow = lane >> 2;            // 16 rows per wave-instruction (4 lanes/row)
  int scol = (lane & 3) * 8;       // element offset in k
  const unsigned short* Abase = A + (size_t)(m0 + w * 32 + srow) * K + scol;
  const unsigned short* Bbase = BT + (size_t)(n0 + w * 32 + srow) * K + scol;
  unsigned short* AsW = As + (w * 32) * 32;  // uniform per wave; HW adds lane*16B
  unsigned short* BsW = Bs + (w * 32) * 32;

  for (int kt = 0; kt < K; kt += 32){
    __syncthreads();
    async_cp16(Abase + kt, AsW);
    async_cp16(Abase + kt + (size_t)16 * K, AsW + 16 * 32);
    async_cp16(Bbase + kt, BsW);
    async_cp16(Bbase + kt + (size_t)16 * K, BsW + 16 * 32);
    __syncthreads();
    short8 af[4], bfr[4];
    for (int im = 0; im < 4; im++)
      af[im] = *(const short8*)(As + (wr * 64 + im * 16 + l16) * 32 + quad * 8);
    for (int in = 0; in < 4; in++)
      bfr[in] = *(const short8*)(Bs + (wc * 64 + in * 16 + l16) * 32 + quad * 8);
    for (int im = 0; im < 4; im++)
      for (int in = 0; in < 4; in++)
        acc[im][in] = __builtin_amdgcn_mfma_f32_16x16x32_bf16(af[im], bfr[in], acc[im][in], 0, 0, 0);
  }

  for (int im = 0; im < 4; im++){
    int row = m0 + wr * 64 + im * 16 + quad * 4;
    for (int in = 0; in < 4; in++){
      int col = n0 + wc * 64 + in * 16 + l16;
      float bb = bias[col];
      f32x4 v = acc[im][in];
      for (int r = 0; r < 4; r++){
        float out = v[r] + bb;
        if (OUT_BF16) ((unsigned short*)Cout)[(size_t)(row + r) * N + col] = ftob(out);
        else          ((float*)Cout)[(size_t)(row + r) * N + col] = out;
      }
    }
  }
}

// ---------------- rmsnorm (bf16-faithful) + 3D rope ----------------
// grid: x = 4096 token rows, y = 0(q)/1(k)
__global__ __launch_bounds__(256) void k_rmsnorm_rope(const unsigned short* __restrict__ QKVr,
        const float* __restrict__ gq, const float* __restrict__ gk,
        const int* __restrict__ grid_sizes, const float* __restrict__ freqs,
        unsigned short* __restrict__ Qh, unsigned short* __restrict__ Kh){
  int row = blockIdx.x;
  int which = blockIdx.y;
  int b = row >> 11, s = row & 2047;
  const unsigned short* xrow = QKVr + (size_t)row * 9216 + which * 3072;
  const float* g = which ? gk : gq;
  unsigned short* out = which ? Kh : Qh;

  int tid = threadIdx.x, w = tid >> 6, lane = tid & 63;
  float ss = 0.f;
  for (int i = tid; i < 3072; i += 256){
    float v = btof(xrow[i]);
    ss += btof(ftob(v * v));        // ref squares in bf16
  }
  for (int off = 32; off; off >>= 1) ss += __shfl_down(ss, off);
  __shared__ float red[4];
  if (lane == 0) red[w] = ss;
  __syncthreads();
  float tot = red[0] + red[1] + red[2] + red[3];
  float m = rb(tot * (1.0f / 3072.0f));
  m = rb(m + rb(1e-6f));
  float rn = rb(rsqrtf(m));

  int f = grid_sizes[b * 3], hh = grid_sizes[b * 3 + 1], ww = grid_sizes[b * 3 + 2];
  int fhw = f * hh * ww;

  for (int p = tid; p < 1536; p += 256){
    int c = p & 63, hd = p >> 6;
    int e0 = hd * 128 + 2 * c;
    float x0 = rb(btof(xrow[e0]) * rn) * rb(g[e0]);
    float x1 = rb(btof(xrow[e0 + 1]) * rn) * rb(g[e0 + 1]);
    float cs = 1.f, sn = 0.f;
    if (s < fhw){
      int pos;
      if (c < 22) pos = s / (hh * ww);          // C1 = 22
      else if (c < 43) pos = (s / ww) % hh;     // C2 = 21
      else pos = s % ww;                        // C3 = 21
      cs = freqs[(pos * 64 + c) * 2];
      sn = freqs[(pos * 64 + c) * 2 + 1];
    }
    float o0 = x0 * cs - x1 * sn;
    float o1 = x0 * sn + x1 * cs;
    size_t ob = ((size_t)((b * 24 + hd) * 2048 + s)) * 128 + 2 * c;
    out[ob]     = ftob(o0);
    out[ob + 1] = ftob(o1);
  }
}

// V: (token-major, +bias already) -> Vt[bh][d][t]   grid: x = bh(48), y = t-tile(32)
// Tile is 64 t-rows x 128 d-cols = 8192 elems -> 32 iterations of 256 threads.
__global__ __launch_bounds__(256) void k_build_vt(const unsigned short* __restrict__ QKVr,
                                                  unsigned short* __restrict__ Vt){
  __shared__ unsigned short tile[64][130];
  int bh = blockIdx.x;
  int b = bh / 24, h = bh % 24;
  int t0 = blockIdx.y * 64;
  for (int i = 0; i < 32; i++){
    int idx = i * 256 + threadIdx.x;          // 0..8191
    int r = idx >> 7, c = idx & 127;          // r: 0..63, c: 0..127
    tile[r][c] = QKVr[(size_t)(b * 2048 + t0 + r) * 9216 + 6144 + h * 128 + c];
  }
  __syncthreads();
  for (int i = 0; i < 32; i++){
    int idx = i * 256 + threadIdx.x;          // 0..8191
    int d = idx >> 6, t = idx & 63;           // d: 0..127, t: 0..63
    Vt[((size_t)bh * 128 + d) * 2048 + t0 + t] = tile[t][d];
  }
}

// ---------------- flash attention ----------------
// grid: x = q-tile (16), y = head (24), z = batch (2); 4 waves, 32 q-rows/wave.
__global__ __launch_bounds__(256) void k_attn(const unsigned short* __restrict__ Q,
              const unsigned short* __restrict__ Kt, const unsigned short* __restrict__ Vt,
              const int* __restrict__ seq_lens, unsigned short* __restrict__ Obuf){
  int qt = blockIdx.x, h = blockIdx.y, b = blockIdx.z;
  int bh = b * 24 + h;
  int tid = threadIdx.x, w = tid >> 6, lane = tid & 63;
  int quad = lane >> 4, l16 = lane & 15;
  int sl = seq_lens[b];
  int nkt = (sl + 63) >> 6;

  __shared__ __align__(16) unsigned short Ks[64 * 128];   // [t][d]
  __shared__ __align__(16) unsigned short Vs[128 * 64];   // [d][t]
  __shared__ __align__(16) unsigned short Ps[4][32 * 64]; // per-wave P [qrow][t]

  const unsigned short* Qb = Q + ((size_t)bh * 2048 + qt * 128 + w * 32) * 128;
  short8 qf[2][4];
  for (int rt = 0; rt < 2; rt++)
    for (int ks = 0; ks < 4; ks++)
      qf[rt][ks] = *(const short8*)(Qb + (rt * 16 + l16) * 128 + ks * 32 + quad * 8);

  f32x4 o[2][8] = {};
  float mrow[2][4], lrow[2][4];
  for (int rt = 0; rt < 2; rt++)
    for (int r = 0; r < 4; r++){ mrow[rt][r] = -1e30f; lrow[rt][r] = 0.f; }

  const float ksc = 0.08838834764831845f * 1.4426950408889634f;  // scale*log2e

  const unsigned short* Kg0 = Kt + (size_t)bh * 2048 * 128;
  const unsigned short* Vg0 = Vt + (size_t)bh * 128 * 2048;

  for (int kt = 0; kt < nkt; kt++){
    int t0 = kt * 64;
    __syncthreads();
    for (int i = 0; i < 4; i++){              // K tile: 64 rows x 256B
      int rowi = w * 16 + i * 4;
      async_cp16(Kg0 + (size_t)(t0 + rowi + quad) * 128 + l16 * 8,
                 (unsigned short*)Ks + rowi * 128);
    }
    for (int i = 0; i < 4; i++){              // Vt tile: 128 rows x 128B
      int rowi = w * 32 + i * 8;
      async_cp16(Vg0 + (size_t)(rowi + (lane >> 3)) * 2048 + t0 + (lane & 7) * 8,
                 (unsigned short*)Vs + rowi * 64);
    }
    __syncthreads();

    f32x4 sac[2][4] = {};
    for (int ks = 0; ks < 4; ks++){
      short8 kf[4];
      for (int ct = 0; ct < 4; ct++)
        kf[ct] = *(const short8*)(Ks + (ct * 16 + l16) * 128 + ks * 32 + quad * 8);
      for (int rt = 0; rt < 2; rt++)
        for (int ct = 0; ct < 4; ct++)
          sac[rt][ct] = __builtin_amdgcn_mfma_f32_16x16x32_bf16(qf[rt][ks], kf[ct], sac[rt][ct], 0, 0, 0);
    }

    if (t0 + 64 > sl){                         // partial tile mask
      for (int ct = 0; ct < 4; ct++)
        if (t0 + ct * 16 + l16 >= sl)
          for (int rt = 0; rt < 2; rt++)
            for (int r = 0; r < 4; r++) sac[rt][ct][r] = -1e30f;
    }

    for (int rt = 0; rt < 2; rt++){
      for (int r = 0; r < 4; r++){
        float mx = fmaxf(fmaxf(sac[rt][0][r], sac[rt][1][r]), fmaxf(sac[rt][2][r], sac[rt][3][r]));
        mx = fmaxf(mx, __shfl_xor(mx, 1));
        mx = fmaxf(mx, __shfl_xor(mx, 2));
        mx = fmaxf(mx, __shfl_xor(mx, 4));
        mx = fmaxf(mx, __shfl_xor(mx, 8));
        float mnew = fmaxf(mrow[rt][r], mx);
        float alpha = exp2f((mrow[rt][r] - mnew) * ksc);
        mrow[rt][r] = mnew;
        float psum = 0.f;
        int prow = (rt * 16 + quad * 4 + r) * 64;
        for (int ct = 0; ct < 4; ct++){
          float p = exp2f((sac[rt][ct][r] - mnew) * ksc);
          unsigned short pb = ftob(p);
          psum += btof(pb);                    // l consistent with bf16 P used in PV
          Ps[w][prow + ct * 16 + l16] = pb;
        }
        psum += __shfl_xor(psum, 1);
        psum += __shfl_xor(psum, 2);
        psum += __shfl_xor(psum, 4);
        psum += __shfl_xor(psum, 8);
        lrow[rt][r] = lrow[rt][r] * alpha + psum;
        for (int dt = 0; dt < 8; dt++) o[rt][dt][r] *= alpha;
      }
    }

    // wave-local: DS ops retire in order; fence compiler reordering + drain writes
    asm volatile("s_waitcnt lgkmcnt(0)" ::: "memory");

    for (int ks = 0; ks < 2; ks++){
      short8 vf[8];
      for (int dt = 0; dt < 8; dt++)
        vf[dt] = *(const short8*)(Vs + (dt * 16 + l16) * 64 + ks * 32 + quad * 8);
      for (int rt = 0; rt < 2; rt++){
        short8 pf = *(const short8*)(&Ps[w][(rt * 16 + l16) * 64 + ks * 32 + quad * 8]);
        for (int dt = 0; dt < 8; dt++)
          o[rt][dt] = __builtin_amdgcn_mfma_f32_16x16x32_bf16(pf, vf[dt], o[rt][dt], 0, 0, 0);
      }
    }
  }

  for (int rt = 0; rt < 2; rt++){
    for (int r = 0; r < 4; r++){
      float inv = 1.0f / lrow[rt][r];
      int s = qt * 128 + w * 32 + rt * 16 + quad * 4 + r;
      size_t base = (size_t)(b * 2048 + s) * 3072 + h * 128;
      for (int dt = 0; dt < 8; dt++)
        Obuf[base + dt * 16 + l16] = ftob(o[rt][dt][r] * inv);
    }
  }
}

// ---------------- launch ----------------

extern "C" void kernel_launch(void* const* d_in, const int* in_sizes, int n_in,
                              void* d_out, int out_size, void* d_ws, size_t ws_size,
                              hipStream_t stream){
  const float* x          = (const float*)d_in[0];
  const int*   seq_lens   = (const int*)d_in[1];
  const int*   grid_sizes = (const int*)d_in[2];
  const float* freqs      = (const float*)d_in[3];
  const float* wq = (const float*)d_in[4];
  const float* bq = (const float*)d_in[5];
  const float* wk = (const float*)d_in[6];
  const float* bk = (const float*)d_in[7];
  const float* wv = (const float*)d_in[8];
  const float* bv = (const float*)d_in[9];
  const float* wo = (const float*)d_in[10];
  const float* bo = (const float*)d_in[11];
  const float* gq = (const float*)d_in[12];
  const float* gk = (const float*)d_in[13];

  char* ws = (char*)d_ws;
  unsigned short* Xb    = (unsigned short*)(ws);               // 25,165,824 B (also Obuf)
  unsigned short* WTqkv = (unsigned short*)(ws + 25165824);    // 56,623,104 B
  unsigned short* woT   = (unsigned short*)(ws + 81788928);    // 18,874,368 B
  float*          bias9 = (float*)(ws + 100663296);            //     36,864 B
  unsigned short* QKVr  = (unsigned short*)(ws + 100700160);   // 75,497,472 B
  unsigned short* Qh    = (unsigned short*)(ws + 176197632);   // 25,165,824 B
  unsigned short* Kh    = (unsigned short*)(ws + 201363456);   // 25,165,824 B
  unsigned short* Vth   = (unsigned short*)(ws + 226529280);   // 25,165,824 B -> 251,695,104 total
  unsigned short* Obuf  = Xb;                                  // Xb dead after QKV GEMM

  k_convert_x<<<12288, 256, 0, stream>>>(x, Xb);
  k_bias<<<36, 256, 0, stream>>>(bq, bk, bv, bias9);
  k_wt<<<dim3(48, 192), 256, 0, stream>>>(wq, wk, wv, wo, WTqkv, woT);
  k_gemm<true><<<dim3(72, 32), 256, 0, stream>>>(Xb, WTqkv, bias9, QKVr, 9216, 3072);
  k_rmsnorm_rope<<<dim3(4096, 2), 256, 0, stream>>>(QKVr, gq, gk, grid_sizes, freqs, Qh, Kh);
  k_build_vt<<<dim3(48, 32), 256, 0, stream>>>(QKVr, Vth);
  k_attn<<<dim3(16, 24, 2), 256, 0, stream>>>(Qh, Kh, Vth, seq_lens, Obuf);
  // Final projection: out = attn_out @ wo + bo, written as FLOAT32 (reference output dtype).
  k_gemm<false><<<dim3(24, 32), 256, 0, stream>>>(Obuf, woT, bo, (float*)d_out, 3072, 3072);
}

// Round 5
// 1034.988 us; speedup vs baseline: 1.0576x; 1.0576x over previous
//
#include <hip/hip_runtime.h>
#include <stdint.h>
#include <stddef.h>

// WanSelfAttention on gfx950.
// R5: XOR chunk-swizzle on all LDS tiles (Ks/Vs/Ps in k_attn, As/Bs in k_gemm)
// to kill 16-way / 8-way bank conflicts. global_load_lds forces contiguous LDS
// layout, so the swizzle is applied by permuting each lane's GLOBAL source
// address at staging time; fragment reads use the same XOR.

typedef __attribute__((ext_vector_type(8))) short short8;
typedef __attribute__((ext_vector_type(4))) float f32x4;
typedef __attribute__((ext_vector_type(4))) unsigned short ushort4v;
typedef __attribute__((address_space(1))) uint32_t gu32;
typedef __attribute__((address_space(3))) uint32_t lu32;

__device__ __forceinline__ float btof(unsigned short u){
  union { float f; uint32_t i; } x; x.i = ((uint32_t)u) << 16; return x.f;
}
__device__ __forceinline__ unsigned short ftob(float f){
  uint32_t u = __builtin_bit_cast(uint32_t, f);
  u += 0x7fffu + ((u >> 16) & 1u);   // RTNE (finite inputs only)
  return (unsigned short)(u >> 16);
}
__device__ __forceinline__ float rb(float f){ return btof(ftob(f)); }

__device__ __forceinline__ void async_cp16(const void* g, void* l){
  __builtin_amdgcn_global_load_lds((gu32*)g, (lu32*)l, 16, 0, 0);
}

// ---------------- converters ----------------

__global__ __launch_bounds__(256) void k_convert_x(const float* __restrict__ x,
                                                   unsigned short* __restrict__ xb){
  int i = (blockIdx.x * 256 + threadIdx.x) * 4;
  float4 v = *(const float4*)(x + i);
  ushort4v o = { ftob(v.x), ftob(v.y), ftob(v.z), ftob(v.w) };
  *(ushort4v*)(xb + i) = o;
}

__global__ __launch_bounds__(256) void k_bias(const float* __restrict__ bq,
                                              const float* __restrict__ bk,
                                              const float* __restrict__ bv,
                                              float* __restrict__ bias9){
  int i = blockIdx.x * 256 + threadIdx.x;     // 0..9215
  const float* s = (i < 3072) ? bq : ((i < 6144) ? bk : bv);
  bias9[i] = s[i % 3072];
}

// Transpose f32 weights (K x N, row-major) into bf16 W^T (N x K) rows.
__global__ __launch_bounds__(256) void k_wt(const float* __restrict__ wq,
                                            const float* __restrict__ wk,
                                            const float* __restrict__ wv,
                                            const float* __restrict__ wo,
                                            unsigned short* __restrict__ WTqkv,
                                            unsigned short* __restrict__ woT){
  __shared__ float tile[64][65];
  int k0 = blockIdx.x * 64;
  int n0g = blockIdx.y * 64;
  const float* src; unsigned short* dst; int col0, drow0;
  if (n0g < 9216){
    int sel = n0g / 3072;
    src = (sel == 0) ? wq : ((sel == 1) ? wk : wv);
    col0 = n0g % 3072; dst = WTqkv; drow0 = n0g;
  } else { src = wo; col0 = n0g - 9216; dst = woT; drow0 = n0g - 9216; }
  for (int i = 0; i < 16; i++){
    int idx = i * 256 + threadIdx.x;
    int r = idx >> 6, c = idx & 63;
    tile[r][c] = src[(size_t)(k0 + r) * 3072 + col0 + c];
  }
  __syncthreads();
  for (int i = 0; i < 16; i++){
    int idx = i * 256 + threadIdx.x;
    int rr = idx >> 6, cc = idx & 63;
    dst[(size_t)(drow0 + rr) * 3072 + k0 + cc] = ftob(tile[cc][rr]);
  }
}

// ---------------- GEMM: C[m][n] = sum_k A[m][k]*BT[n][k] + bias[n] ----------------
// 128x128 tile, BK=32, 4 waves (2x2), 4x4 MFMA tiles per wave.
// LDS rows = 32 elems = 64 B = 4 chunks of 16 B; swizzle chunk' = chunk ^ (row&3).
template <bool OUT_BF16>
__global__ __launch_bounds__(256) void k_gemm(const unsigned short* __restrict__ A,
                                              const unsigned short* __restrict__ BT,
                                              const float* __restrict__ bias,
                                              void* __restrict__ Cout, int N, int K){
  __shared__ __align__(16) unsigned short As[128 * 32];
  __shared__ __align__(16) unsigned short Bs[128 * 32];
  int tid = threadIdx.x;
  int w = tid >> 6, lane = tid & 63;
  int quad = lane >> 4, l16 = lane & 15;
  int m0 = blockIdx.y * 128, n0 = blockIdx.x * 128;
  int wr = w >> 1, wc = w & 1;

  f32x4 acc[4][4] = {};

  int srow = lane >> 2;                              // LDS row this lane fills
  int scol = ((lane & 3) ^ (srow & 3)) * 8;          // swizzled global chunk
  const unsigned short* Abase = A + (size_t)(m0 + w * 32 + srow) * K + scol;
  const unsigned short* Bbase = BT + (size_t)(n0 + w * 32 + srow) * K + scol;
  unsigned short* AsW = As + (w * 32) * 32;  // uniform per wave; HW adds lane*16B
  unsigned short* BsW = Bs + (w * 32) * 32;

  for (int kt = 0; kt < K; kt += 32){
    __syncthreads();
    async_cp16(Abase + kt, AsW);
    async_cp16(Abase + kt + (size_t)16 * K, AsW + 16 * 32);
    async_cp16(Bbase + kt, BsW);
    async_cp16(Bbase + kt + (size_t)16 * K, BsW + 16 * 32);
    __syncthreads();
    short8 af[4], bfr[4];
    int csw = (quad ^ (l16 & 3)) * 8;                // swizzled read chunk
    for (int im = 0; im < 4; im++)
      af[im] = *(const short8*)(As + (wr * 64 + im * 16 + l16) * 32 + csw);
    for (int in = 0; in < 4; in++)
      bfr[in] = *(const short8*)(Bs + (wc * 64 + in * 16 + l16) * 32 + csw);
    for (int im = 0; im < 4; im++)
      for (int in = 0; in < 4; in++)
        acc[im][in] = __builtin_amdgcn_mfma_f32_16x16x32_bf16(af[im], bfr[in], acc[im][in], 0, 0, 0);
  }

  for (int im = 0; im < 4; im++){
    int row = m0 + wr * 64 + im * 16 + quad * 4;
    for (int in = 0; in < 4; in++){
      int col = n0 + wc * 64 + in * 16 + l16;
      float bb = bias[col];
      f32x4 v = acc[im][in];
      for (int r = 0; r < 4; r++){
        float out = v[r] + bb;
        if (OUT_BF16) ((unsigned short*)Cout)[(size_t)(row + r) * N + col] = ftob(out);
        else          ((float*)Cout)[(size_t)(row + r) * N + col] = out;
      }
    }
  }
}

// ---------------- rmsnorm (bf16-faithful) + 3D rope ----------------
__global__ __launch_bounds__(256) void k_rmsnorm_rope(const unsigned short* __restrict__ QKVr,
        const float* __restrict__ gq, const float* __restrict__ gk,
        const int* __restrict__ grid_sizes, const float* __restrict__ freqs,
        unsigned short* __restrict__ Qh, unsigned short* __restrict__ Kh){
  int row = blockIdx.x;
  int which = blockIdx.y;
  int b = row >> 11, s = row & 2047;
  const unsigned short* xrow = QKVr + (size_t)row * 9216 + which * 3072;
  const float* g = which ? gk : gq;
  unsigned short* out = which ? Kh : Qh;

  int tid = threadIdx.x, w = tid >> 6, lane = tid & 63;
  float ss = 0.f;
  for (int i = tid; i < 3072; i += 256){
    float v = btof(xrow[i]);
    ss += btof(ftob(v * v));        // ref squares in bf16
  }
  for (int off = 32; off; off >>= 1) ss += __shfl_down(ss, off);
  __shared__ float red[4];
  if (lane == 0) red[w] = ss;
  __syncthreads();
  float tot = red[0] + red[1] + red[2] + red[3];
  float m = rb(tot * (1.0f / 3072.0f));
  m = rb(m + rb(1e-6f));
  float rn = rb(rsqrtf(m));

  int f = grid_sizes[b * 3], hh = grid_sizes[b * 3 + 1], ww = grid_sizes[b * 3 + 2];
  int fhw = f * hh * ww;

  for (int p = tid; p < 1536; p += 256){
    int c = p & 63, hd = p >> 6;
    int e0 = hd * 128 + 2 * c;
    float x0 = rb(btof(xrow[e0]) * rn) * rb(g[e0]);
    float x1 = rb(btof(xrow[e0 + 1]) * rn) * rb(g[e0 + 1]);
    float cs = 1.f, sn = 0.f;
    if (s < fhw){
      int pos;
      if (c < 22) pos = s / (hh * ww);          // C1 = 22
      else if (c < 43) pos = (s / ww) % hh;     // C2 = 21
      else pos = s % ww;                        // C3 = 21
      cs = freqs[(pos * 64 + c) * 2];
      sn = freqs[(pos * 64 + c) * 2 + 1];
    }
    float o0 = x0 * cs - x1 * sn;
    float o1 = x0 * sn + x1 * cs;
    size_t ob = ((size_t)((b * 24 + hd) * 2048 + s)) * 128 + 2 * c;
    out[ob]     = ftob(o0);
    out[ob + 1] = ftob(o1);
  }
}

// V: token-major -> Vt[bh][d][t]
__global__ __launch_bounds__(256) void k_build_vt(const unsigned short* __restrict__ QKVr,
                                                  unsigned short* __restrict__ Vt){
  __shared__ unsigned short tile[64][130];
  int bh = blockIdx.x;
  int b = bh / 24, h = bh % 24;
  int t0 = blockIdx.y * 64;
  for (int i = 0; i < 32; i++){
    int idx = i * 256 + threadIdx.x;
    int r = idx >> 7, c = idx & 127;
    tile[r][c] = QKVr[(size_t)(b * 2048 + t0 + r) * 9216 + 6144 + h * 128 + c];
  }
  __syncthreads();
  for (int i = 0; i < 32; i++){
    int idx = i * 256 + threadIdx.x;
    int d = idx >> 6, t = idx & 63;
    Vt[((size_t)bh * 128 + d) * 2048 + t0 + t] = tile[t][d];
  }
}

// ---------------- flash attention ----------------
// grid: x = q-tile (16), y = head (24), z = batch (2); 4 waves, 32 q-rows/wave.
// LDS swizzle: Ks rows 256B/16 chunks, chunk' = chunk ^ (row&15);
//              Vs/Ps rows 128B/8 chunks, chunk' = chunk ^ (row&7).
__global__ __launch_bounds__(256) void k_attn(const unsigned short* __restrict__ Q,
              const unsigned short* __restrict__ Kt, const unsigned short* __restrict__ Vt,
              const int* __restrict__ seq_lens, unsigned short* __restrict__ Obuf){
  int qt = blockIdx.x, h = blockIdx.y, b = blockIdx.z;
  int bh = b * 24 + h;
  int tid = threadIdx.x, w = tid >> 6, lane = tid & 63;
  int quad = lane >> 4, l16 = lane & 15;
  int sl = seq_lens[b];
  int nkt = (sl + 63) >> 6;

  __shared__ __align__(16) unsigned short Ks[64 * 128];   // [t][d] swizzled
  __shared__ __align__(16) unsigned short Vs[128 * 64];   // [d][t] swizzled
  __shared__ __align__(16) unsigned short Ps[4][32 * 64]; // per-wave P, swizzled

  const unsigned short* Qb = Q + ((size_t)bh * 2048 + qt * 128 + w * 32) * 128;
  short8 qf[2][4];
  for (int rt = 0; rt < 2; rt++)
    for (int ks = 0; ks < 4; ks++)
      qf[rt][ks] = *(const short8*)(Qb + (rt * 16 + l16) * 128 + ks * 32 + quad * 8);

  f32x4 o[2][8] = {};
  float mrow[2][4], lrow[2][4];
  for (int rt = 0; rt < 2; rt++)
    for (int r = 0; r < 4; r++){ mrow[rt][r] = -1e30f; lrow[rt][r] = 0.f; }

  const float ksc = 0.08838834764831845f * 1.4426950408889634f;  // scale*log2e

  const unsigned short* Kg0 = Kt + (size_t)bh * 2048 * 128;
  const unsigned short* Vg0 = Vt + (size_t)bh * 128 * 2048;

  int vrow = lane >> 3;                      // Vs staging: row within 8-row group
  int vchunk = (lane & 7) ^ (vrow & 7);      // swizzled global chunk for Vs

  for (int kt = 0; kt < nkt; kt++){
    int t0 = kt * 64;
    __syncthreads();
    for (int i = 0; i < 4; i++){              // K tile: 64 rows x 256B, 4 rows/wave-op
      int rowi = w * 16 + i * 4;
      int kchunk = l16 ^ (i * 4 + quad);      // swizzled global chunk (row&15 = i*4+quad)
      async_cp16(Kg0 + (size_t)(t0 + rowi + quad) * 128 + kchunk * 8,
                 (unsigned short*)Ks + rowi * 128);
    }
    for (int i = 0; i < 4; i++){              // Vt tile: 128 rows x 128B, 8 rows/wave-op
      int rowi = w * 32 + i * 8;
      async_cp16(Vg0 + (size_t)(rowi + vrow) * 2048 + t0 + vchunk * 8,
                 (unsigned short*)Vs + rowi * 64);
    }
    __syncthreads();

    f32x4 sac[2][4] = {};
    for (int ks = 0; ks < 4; ks++){
      int kcs = ((ks * 4 + quad) ^ l16) * 8;  // swizzled Ks read chunk
      short8 kf[4];
      for (int ct = 0; ct < 4; ct++)
        kf[ct] = *(const short8*)(Ks + (ct * 16 + l16) * 128 + kcs);
      for (int rt = 0; rt < 2; rt++)
        for (int ct = 0; ct < 4; ct++)
          sac[rt][ct] = __builtin_amdgcn_mfma_f32_16x16x32_bf16(qf[rt][ks], kf[ct], sac[rt][ct], 0, 0, 0);
    }

    if (t0 + 64 > sl){                         // partial tile mask
      for (int ct = 0; ct < 4; ct++)
        if (t0 + ct * 16 + l16 >= sl)
          for (int rt = 0; rt < 2; rt++)
            for (int r = 0; r < 4; r++) sac[rt][ct][r] = -1e30f;
    }

    for (int rt = 0; rt < 2; rt++){
      for (int r = 0; r < 4; r++){
        float mx = fmaxf(fmaxf(sac[rt][0][r], sac[rt][1][r]), fmaxf(sac[rt][2][r], sac[rt][3][r]));
        mx = fmaxf(mx, __shfl_xor(mx, 1));
        mx = fmaxf(mx, __shfl_xor(mx, 2));
        mx = fmaxf(mx, __shfl_xor(mx, 4));
        mx = fmaxf(mx, __shfl_xor(mx, 8));
        float mnew = fmaxf(mrow[rt][r], mx);
        float alpha = exp2f((mrow[rt][r] - mnew) * ksc);
        mrow[rt][r] = mnew;
        float psum = 0.f;
        int pr = rt * 16 + quad * 4 + r;       // P row this lane writes
        int prsw = (quad * 4 + r) & 7;         // row&7 for swizzle
        for (int ct = 0; ct < 4; ct++){
          float p = exp2f((sac[rt][ct][r] - mnew) * ksc);
          unsigned short pb = ftob(p);
          psum += btof(pb);                    // l consistent with bf16 P used in PV
          int j = ct * 16 + l16;               // column
          int cidx = ((j >> 3) ^ prsw) * 8 + (j & 7);
          Ps[w][pr * 64 + cidx] = pb;
        }
        psum += __shfl_xor(psum, 1);
        psum += __shfl_xor(psum, 2);
        psum += __shfl_xor(psum, 4);
        psum += __shfl_xor(psum, 8);
        lrow[rt][r] = lrow[rt][r] * alpha + psum;
        for (int dt = 0; dt < 8; dt++) o[rt][dt][r] *= alpha;
      }
    }

    // wave-local: DS ops retire in order; fence compiler reordering + drain writes
    asm volatile("s_waitcnt lgkmcnt(0)" ::: "memory");

    for (int ks = 0; ks < 2; ks++){
      int vcs = ((ks * 4 + quad) ^ (l16 & 7)) * 8;  // swizzled Vs/Ps read chunk
      short8 vf[8];
      for (int dt = 0; dt < 8; dt++)
        vf[dt] = *(const short8*)(Vs + (dt * 16 + l16) * 64 + vcs);
      for (int rt = 0; rt < 2; rt++){
        short8 pf = *(const short8*)(&Ps[w][(rt * 16 + l16) * 64 + vcs]);
        for (int dt = 0; dt < 8; dt++)
          o[rt][dt] = __builtin_amdgcn_mfma_f32_16x16x32_bf16(pf, vf[dt], o[rt][dt], 0, 0, 0);
      }
    }
  }

  for (int rt = 0; rt < 2; rt++){
    for (int r = 0; r < 4; r++){
      float inv = 1.0f / lrow[rt][r];
      int s = qt * 128 + w * 32 + rt * 16 + quad * 4 + r;
      size_t base = (size_t)(b * 2048 + s) * 3072 + h * 128;
      for (int dt = 0; dt < 8; dt++)
        Obuf[base + dt * 16 + l16] = ftob(o[rt][dt][r] * inv);
    }
  }
}

// ---------------- launch ----------------

extern "C" void kernel_launch(void* const* d_in, const int* in_sizes, int n_in,
                              void* d_out, int out_size, void* d_ws, size_t ws_size,
                              hipStream_t stream){
  const float* x          = (const float*)d_in[0];
  const int*   seq_lens   = (const int*)d_in[1];
  const int*   grid_sizes = (const int*)d_in[2];
  const float* freqs      = (const float*)d_in[3];
  const float* wq = (const float*)d_in[4];
  const float* bq = (const float*)d_in[5];
  const float* wk = (const float*)d_in[6];
  const float* bk = (const float*)d_in[7];
  const float* wv = (const float*)d_in[8];
  const float* bv = (const float*)d_in[9];
  const float* wo = (const float*)d_in[10];
  const float* bo = (const float*)d_in[11];
  const float* gq = (const float*)d_in[12];
  const float* gk = (const float*)d_in[13];

  char* ws = (char*)d_ws;
  unsigned short* Xb    = (unsigned short*)(ws);               // 25,165,824 B (also Obuf)
  unsigned short* WTqkv = (unsigned short*)(ws + 25165824);    // 56,623,104 B
  unsigned short* woT   = (unsigned short*)(ws + 81788928);    // 18,874,368 B
  float*          bias9 = (float*)(ws + 100663296);            //     36,864 B
  unsigned short* QKVr  = (unsigned short*)(ws + 100700160);   // 75,497,472 B
  unsigned short* Qh    = (unsigned short*)(ws + 176197632);   // 25,165,824 B
  unsigned short* Kh    = (unsigned short*)(ws + 201363456);   // 25,165,824 B
  unsigned short* Vth   = (unsigned short*)(ws + 226529280);   // 25,165,824 B
  unsigned short* Obuf  = Xb;                                  // Xb dead after QKV GEMM

  k_convert_x<<<12288, 256, 0, stream>>>(x, Xb);
  k_bias<<<36, 256, 0, stream>>>(bq, bk, bv, bias9);
  k_wt<<<dim3(48, 192), 256, 0, stream>>>(wq, wk, wv, wo, WTqkv, woT);
  k_gemm<true><<<dim3(72, 32), 256, 0, stream>>>(Xb, WTqkv, bias9, QKVr, 9216, 3072);
  k_rmsnorm_rope<<<dim3(4096, 2), 256, 0, stream>>>(QKVr, gq, gk, grid_sizes, freqs, Qh, Kh);
  k_build_vt<<<dim3(48, 32), 256, 0, stream>>>(QKVr, Vth);
  k_attn<<<dim3(16, 24, 2), 256, 0, stream>>>(Qh, Kh, Vth, seq_lens, Obuf);
  k_gemm<false><<<dim3(24, 32), 256, 0, stream>>>(Obuf, woT, bo, (float*)d_out, 3072, 3072);
}